// Round 2
// baseline (348.847 us; speedup 1.0000x reference)
//
#include <hip/hip_runtime.h>
#include <hip/hip_bf16.h>
#include <math.h>

// Problem constants
#define TS   24
#define NH   4
#define HD   128
#define D    512
#define NB   64
#define SEQ  512
#define NTOT (NB*SEQ)   // 32768

typedef __bf16 bf16;
typedef __bf16 bf16x8 __attribute__((ext_vector_type(8)));
typedef float  f32x4  __attribute__((ext_vector_type(4)));

// Workspace layout (float offsets)
#define OFF_QU  0        // [64][512]   qu[b][h*128+e]  (includes bq)
#define OFF_QT  32768    // [24][512]   qt[t][h*128+e]
#define OFF_K   45056    // [24][512]   k[kk][h*128+e]  (includes bk)
#define OFF_V   57344    // [24][512]   v[kk][h*128+e]  (includes bv)
#define OFF_SU  69632    // [64][4][24] scale*log2e * qu.k
#define OFF_ST  75776    // [24][4][24] scale*log2e * qt.k
#define OFF_BSW 78080    // bf16 region: [12 groups][544 cols][8 k] = 52224 bf16

// 32-float partial dot (8 float4 pairs), fully unrolled
static __device__ __forceinline__ float dot32(const float* __restrict__ a,
                                              const float* __restrict__ b) {
    const float4* a4 = (const float4*)a;
    const float4* b4 = (const float4*)b;
    float acc = 0.f;
    #pragma unroll
    for (int i = 0; i < 8; ++i) {
        float4 x = a4[i], y = b4[i];
        acc += x.x*y.x + x.y*y.y + x.z*y.z + x.w*y.w;
    }
    return acc;
}

// ---------------------------------------------------------------------------
// K1: projections, 4-way split per output for occupancy (1088 blocks).
// Each output's 512-dot is split across lanes {4o, 4o+1, 4o+2, 4o+3};
// partials combined via shfl_xor (group-of-4 is lane-aligned since q = tid&3).
// ---------------------------------------------------------------------------
__global__ __launch_bounds__(256) void k1_proj(
    const float* __restrict__ timeslot, const int* __restrict__ user_x,
    const float* __restrict__ upt,
    const float* __restrict__ Wq, const float* __restrict__ bq,
    const float* __restrict__ Wk, const float* __restrict__ bk,
    const float* __restrict__ Wv, const float* __restrict__ bv,
    float* __restrict__ ws)
{
    int gid = blockIdx.x * 256 + threadIdx.x;     // 278528 threads total
    int o = gid >> 2, q = gid & 3;                // o < 69632
    if (o < 32768) {                              // qu[b][he]
        int he = o >> 6, b = o & 63;
        const float4* wrow = (const float4*)(Wq + (size_t)he * 1024) + q*32;
        int u = user_x[b];
        const float4* urow = (const float4*)(upt + (size_t)u * 512) + q*32;
        float acc = 0.f;
        #pragma unroll 8
        for (int d = 0; d < 32; ++d) {
            float4 w = wrow[d], x = urow[d];
            acc += w.x*x.x + w.y*x.y + w.z*x.z + w.w*x.w;
        }
        acc += __shfl_xor(acc, 1);
        acc += __shfl_xor(acc, 2);
        if (q == 0) ws[OFF_QU + b*512 + he] = acc + bq[he];
    } else {                                      // qt / k / v : [t][he]
        int idx = o - 32768;
        int sec = idx / 12288;                    // 0: qt, 1: k, 2: v
        int r   = idx % 12288;
        int he  = r / 24, t = r % 24;             // t fastest -> W row ~wave-uniform
        const float* wbase; float bias; int outoff;
        if (sec == 0)      { wbase = Wq + (size_t)he*1024 + 512; bias = 0.f;    outoff = OFF_QT; }
        else if (sec == 1) { wbase = Wk + (size_t)he*512;        bias = bk[he]; outoff = OFF_K;  }
        else               { wbase = Wv + (size_t)he*512;        bias = bv[he]; outoff = OFF_V;  }
        const float4* w4 = (const float4*)wbase + q*32;
        const float4* x4 = (const float4*)(timeslot + t*512) + q*32;
        float acc = 0.f;
        #pragma unroll 8
        for (int d = 0; d < 32; ++d) {
            float4 w = w4[d], x = x4[d];
            acc += w.x*x.x + w.y*x.y + w.z*x.z + w.w*x.w;
        }
        acc += __shfl_xor(acc, 1);
        acc += __shfl_xor(acc, 2);
        if (q == 0) ws[outoff + t*512 + he] = acc + bias;
    }
}

// ---------------------------------------------------------------------------
// K2: score tables SU/ST (pre-scaled by 1/sqrt(128)*log2e) and folded
// B matrix Bsw = [VU | VT | zero-pad] in MFMA-B fragment order.
// 4-way split per output (948 blocks).
// ---------------------------------------------------------------------------
__global__ __launch_bounds__(256) void k2_small(
    const float* __restrict__ Wu, const float* __restrict__ Wt,
    float* __restrict__ ws)
{
    const float SCL = 1.4426950408889634f / sqrtf(128.0f);  // log2(e) * 1/sqrt(HD)
    int gid = blockIdx.x * 256 + threadIdx.x;     // 242688 threads total
    int o = gid >> 2, q = gid & 3;                // o < 60672
    int qo = q * 32;                              // float offset of this lane's quarter
    bf16* Bsw = (bf16*)(ws + OFF_BSW);
    if (o < 6144) {                               // SU[(b*4+h)*24+kk]
        int kk = o % 24, h = (o / 24) & 3, b = o / 96;
        float acc = dot32(ws + OFF_QU + b*512 + h*128 + qo,
                          ws + OFF_K  + kk*512 + h*128 + qo);
        acc += __shfl_xor(acc, 1);
        acc += __shfl_xor(acc, 2);
        if (q == 0) ws[OFF_SU + o] = acc * SCL;
    } else if (o < 8448) {                        // ST[(t*4+h)*24+kk]
        int i = o - 6144;
        int kk = i % 24, h = (i / 24) & 3, t = i / 96;
        float acc = dot32(ws + OFF_QT + t*512 + h*128 + qo,
                          ws + OFF_K  + kk*512 + h*128 + qo);
        acc += __shfl_xor(acc, 1);
        acc += __shfl_xor(acc, 2);
        if (q == 0) ws[OFF_ST + i] = acc * SCL;
    } else if (o < 57600) {                       // VU -> Bsw cols 0..511
        int i = o - 8448;
        int c = i & 511, r96 = i >> 9;
        int h = r96 / 24, kk = r96 % 24;
        float acc = dot32(ws + OFF_V + kk*512 + h*128 + qo,
                          Wu + (size_t)c*512 + h*128 + qo);
        acc += __shfl_xor(acc, 1);
        acc += __shfl_xor(acc, 2);
        if (q == 0) Bsw[((r96 >> 3)*544 + c)*8 + (r96 & 7)] = (bf16)acc;
    } else if (o < 59904) {                       // VT -> Bsw cols 512..535
        int i = o - 57600;
        int j = i % 24, r96 = i / 24;
        int h = r96 / 24, kk = r96 % 24;
        float acc = dot32(ws + OFF_V + kk*512 + h*128 + qo,
                          Wt + (size_t)j*512 + h*128 + qo);
        acc += __shfl_xor(acc, 1);
        acc += __shfl_xor(acc, 2);
        if (q == 0) Bsw[((r96 >> 3)*544 + 512 + j)*8 + (r96 & 7)] = (bf16)acc;
    } else {                                      // zero pad cols 536..543 (o < 60672)
        int i = o - 59904;
        int grp = i >> 6, rem = i & 63;
        int c = 536 + (rem >> 3), j = rem & 7;
        if (q == 0) Bsw[(grp*544 + c)*8 + j] = (bf16)0.f;
    }
}

// ---------------------------------------------------------------------------
// K3 (main): block = 128 consecutive n (same b), 512 threads = 8 waves
// (2 waves/SIMD for latency hiding).
// Phase 1: attn -> LDS (bf16, A-fragment row-major, stride 104), 1 task/thread.
// Phase 2: MFMA GEMM [128 x 96] x [96 x 544]; each wave owns ONE 16-row tile.
// ---------------------------------------------------------------------------
__global__ __launch_bounds__(512) void k3_main(
    const int* __restrict__ hour_x, const int* __restrict__ hour_mask,
    const float* __restrict__ b_unify, const float* __restrict__ b_time,
    const float* __restrict__ ws, float* __restrict__ out)
{
    __shared__ int  maskL[128 * 24];                 // 12 KB
    __shared__ int  hourL[128];
    __shared__ __align__(16) bf16 attnL[128][104];   // 96 used, pad to 104 (26.6 KB)

    int tid = threadIdx.x;
    int n0  = blockIdx.x * 128;
    int b   = n0 >> 9;

    // stage mask rows (contiguous 12KB region, int4) + hours
    {
        const int4* src = (const int4*)(hour_mask + (size_t)n0 * 24);
        int4* dst = (int4*)maskL;
        for (int i = tid; i < 128 * 24 / 4; i += 512)
            dst[i] = src[i];
        if (tid < 128) hourL[tid] = hour_x[n0 + tid];
    }
    __syncthreads();

    // attention weights: 512 tasks (h, row), 1 per thread
    {
        int h = tid >> 7, row = tid & 127;
        int t = hourL[row];
        const float* su = ws + OFF_SU + (b*4 + h)*24;
        const float* st = ws + OFF_ST + (t*4 + h)*24;
        const int*   m  = maskL + row*24;
        float w[24]; float sum = 0.f;
        #pragma unroll
        for (int kk = 0; kk < 24; ++kk) {
            float e = exp2f(su[kk] + st[kk]);   // exp(score), softmax-shift-free
            e = m[kk] ? 0.f : e;
            w[kk] = e; sum += e;
        }
        float inv = 1.f / sum;                  // k=0 never masked -> sum > 0
        #pragma unroll
        for (int kk = 0; kk < 24; ++kk)
            attnL[row][h*24 + kk] = (bf16)(w[kk] * inv);
    }
    __syncthreads();

    // GEMM phase: wave wv owns rows wv*16..wv*16+15 (one 16-row tile)
    const bf16* Bsw = (const bf16*)(ws + OFF_BSW);
    int wv = tid >> 6, l = tid & 63;
    int quad = l >> 4, cl = l & 15;
    int r0 = wv*16 + cl;

    bf16x8 a0 = *(const bf16x8*)&attnL[r0][ 0 + quad*8];
    bf16x8 a1 = *(const bf16x8*)&attnL[r0][32 + quad*8];
    bf16x8 a2 = *(const bf16x8*)&attnL[r0][64 + quad*8];

    int nbase = n0 + wv*16 + quad*4;

    // cols 0..511: at_emb
    for (int ct = 0; ct < 32; ++ct) {
        int col = ct*16 + cl;
        const bf16* bp = Bsw + ((size_t)(quad*544 + col)) * 8;
        bf16x8 b0 = *(const bf16x8*)(bp);
        bf16x8 b1 = *(const bf16x8*)(bp + 4*544*8);
        bf16x8 b2 = *(const bf16x8*)(bp + 8*544*8);
        f32x4 acc = {0.f, 0.f, 0.f, 0.f};
        acc = __builtin_amdgcn_mfma_f32_16x16x32_bf16(a0, b0, acc, 0, 0, 0);
        acc = __builtin_amdgcn_mfma_f32_16x16x32_bf16(a1, b1, acc, 0, 0, 0);
        acc = __builtin_amdgcn_mfma_f32_16x16x32_bf16(a2, b2, acc, 0, 0, 0);
        float bias = b_unify[col];
        #pragma unroll
        for (int r = 0; r < 4; ++r)
            out[(size_t)(nbase + r)*512 + col] = acc[r] + bias;
    }

    // cols 512..535: time logits (col 536..543 are zero-pad, skipped)
    float* tl_out = out + (size_t)NTOT * 512;
    for (int ct = 32; ct < 34; ++ct) {
        int col = ct*16 + cl;
        int cc  = col - 512;
        const bf16* bp = Bsw + ((size_t)(quad*544 + col)) * 8;
        bf16x8 b0 = *(const bf16x8*)(bp);
        bf16x8 b1 = *(const bf16x8*)(bp + 4*544*8);
        bf16x8 b2 = *(const bf16x8*)(bp + 8*544*8);
        f32x4 acc = {0.f, 0.f, 0.f, 0.f};
        acc = __builtin_amdgcn_mfma_f32_16x16x32_bf16(a0, b0, acc, 0, 0, 0);
        acc = __builtin_amdgcn_mfma_f32_16x16x32_bf16(a1, b1, acc, 0, 0, 0);
        acc = __builtin_amdgcn_mfma_f32_16x16x32_bf16(a2, b2, acc, 0, 0, 0);
        if (cc < 24) {
            float bias = b_time[cc];
            #pragma unroll
            for (int r = 0; r < 4; ++r)
                tl_out[(size_t)(nbase + r)*24 + cc] = acc[r] + bias;
        }
    }
}

// ---------------------------------------------------------------------------
extern "C" void kernel_launch(void* const* d_in, const int* in_sizes, int n_in,
                              void* d_out, int out_size, void* d_ws, size_t ws_size,
                              hipStream_t stream) {
    const float* timeslot = (const float*)d_in[0];
    // d_in[1] smoothed_timeslot_embedded: unused by reference
    // d_in[2] user_embedded: unused by reference
    const int*   user_x   = (const int*)d_in[3];
    const int*   hour_x   = (const int*)d_in[4];
    const int*   hour_mask= (const int*)d_in[5];
    const float* upt      = (const float*)d_in[6];
    const float* Wq       = (const float*)d_in[7];
    const float* bq       = (const float*)d_in[8];
    const float* Wk       = (const float*)d_in[9];
    const float* bk       = (const float*)d_in[10];
    const float* Wv       = (const float*)d_in[11];
    const float* bv       = (const float*)d_in[12];
    const float* Wu       = (const float*)d_in[13];
    const float* b_unify  = (const float*)d_in[14];
    const float* Wt       = (const float*)d_in[15];
    const float* b_time   = (const float*)d_in[16];

    float* ws  = (float*)d_ws;   // uses ~417 KB of workspace
    float* out = (float*)d_out;

    k1_proj <<<1088, 256, 0, stream>>>(timeslot, user_x, upt, Wq, bq, Wk, bk, Wv, bv, ws);
    k2_small<<<948,  256, 0, stream>>>(Wu, Wt, ws);
    k3_main <<<256,  512, 0, stream>>>(hour_x, hour_mask, b_unify, b_time, ws, out);
}